// Round 11
// baseline (165.499 us; speedup 1.0000x reference)
//
#include <hip/hip_runtime.h>
#include <hip/hip_bf16.h>

#define B_  8
#define C_  384
#define N_  1024
#define NH_ 12
#define HD_ 32
#define D3_ 1152   // 3*C

typedef __bf16 bf16x8 __attribute__((ext_vector_type(8)));
typedef __bf16 bf16x2 __attribute__((ext_vector_type(2)));
typedef float  f32x4  __attribute__((ext_vector_type(4)));

typedef const __attribute__((address_space(1))) unsigned int guint;
typedef __attribute__((address_space(3))) unsigned int luint;

__device__ __forceinline__ float b2f(ushort u) {
    return __uint_as_float(((unsigned int)u) << 16);
}
__device__ __forceinline__ ushort f2b(float f) {
    unsigned int i = __float_as_uint(f);
    unsigned int r = i + 0x7fffu + ((i >> 16) & 1u);  // RNE
    return (ushort)(r >> 16);
}
// packed fp32x2 -> bf16x2 (RNE)
__device__ __forceinline__ unsigned pk2(float a, float b) {
#if __has_builtin(__builtin_amdgcn_cvt_pk_bf16_f32)
    bf16x2 t = __builtin_amdgcn_cvt_pk_bf16_f32(a, b);
    return __builtin_bit_cast(unsigned, t);
#else
    return (unsigned)f2b(a) | ((unsigned)f2b(b) << 16);
#endif
}

#if __has_builtin(__builtin_amdgcn_exp2f)
#define EXP2 __builtin_amdgcn_exp2f
#else
#define EXP2 exp2f
#endif

__device__ __forceinline__ void gl2lds16(const void* g, void* l) {
    __builtin_amdgcn_global_load_lds((guint*)g, (luint*)l, 16, 0, 0);
}

#define C1_ 0.25505654204433796f   // scale * log2e
#define C2_ 1.4426950408889634f    // log2e
#define TS_ 3972                   // padded per-head table stride (16B-aligned)

// ---------------------------------------------------------------------------
// setup2: weight conversion + bias-table prep (xtrans now fused into qkv).
// Grid: [0,578) prep, [578,590) tabT.
// tabT[h][i] = rpb[3968-i][h] * log2e   (full 2D reversal == 1D reversal)
// ---------------------------------------------------------------------------
__global__ __launch_bounds__(256) void setup2(
    const float* __restrict__ q_w, const float* __restrict__ kv_w,
    const float* __restrict__ proj_w, const float* __restrict__ q_b,
    const float* __restrict__ kv_b, const float* __restrict__ tab,
    float* __restrict__ tabT, ushort* __restrict__ Wall,
    ushort* __restrict__ PW, float* __restrict__ ballf)
{
    const int bx = blockIdx.x, tid = threadIdx.x;

    if (bx < 578) {
        // ---- prep: weights fp32 -> bf16; bias concat fp32 ----
        const int NW4 = 110592, NP4 = 36864, NB4 = 288;
        int t = bx * 256 + tid;
        if (t < NW4) {
            int e = t * 4;
            float4 f = (e < 147456) ? *(const float4*)(q_w + e)
                                    : *(const float4*)(kv_w + e - 147456);
            union { uint2 u; ushort s[4]; } o;
            o.u.x = pk2(f.x, f.y); o.u.y = pk2(f.z, f.w);
            *(uint2*)(Wall + e) = o.u;
        } else if (t < NW4 + NP4) {
            int e = (t - NW4) * 4;
            float4 f = *(const float4*)(proj_w + e);
            union { uint2 u; ushort s[4]; } o;
            o.u.x = pk2(f.x, f.y); o.u.y = pk2(f.z, f.w);
            *(uint2*)(PW + e) = o.u;
        } else if (t < NW4 + NP4 + NB4) {
            int e = (t - NW4 - NP4) * 4;
            float4 f = (e < 384) ? *(const float4*)(q_b + e)
                                 : *(const float4*)(kv_b + e - 384);
            *(float4*)(ballf + e) = f;
        }
    } else {
        // ---- tabT: per-head fully-reversed, log2e-scaled table ----
        int h = bx - 578;
        for (int i = tid; i < 3969; i += 256)
            tabT[h * TS_ + i] = tab[(size_t)(3968 - i) * NH_ + h] * C2_;
        if (tid < 3) tabT[h * TS_ + 3969 + tid] = 0.0f;
    }
}

// ---------------------------------------------------------------------------
// qkv_gemm6: 128x128 tile; x fp32 transposed+converted in-LDS per k-iter
// (hidden under async W global_load_lds). No xT tensor, no xtrans kernel.
// Q/K blocks: W as A-operand -> packed stores to Qt/Kt[b][h][n][32].
// V blocks:   x as A-operand -> fused-transpose packed stores to Vtc.
// Q pre-scaled by scale*log2e.
// As layout: [n][c], padded stride 34 ushorts (b128-read aligned, ~2-way banks).
// ---------------------------------------------------------------------------
__global__ __launch_bounds__(256) void qkv_gemm6(
    const float* __restrict__ x, const ushort* __restrict__ Wall,
    const float* __restrict__ ballf, ushort* __restrict__ Qt,
    ushort* __restrict__ Kt, ushort* __restrict__ Vtc)
{
    const int b = blockIdx.z, n0 = blockIdx.x * 128, d0 = blockIdx.y * 128;
    __shared__ ushort As[128 * 34 + 8];
    __shared__ ushort Bs[128 * 32];
    const int tid = threadIdx.x;
    const int lane = tid & 63, wave = tid >> 6;
    const int quad = lane >> 4, l16 = lane & 15;
    const int wn = (wave & 1) * 64, wd = (wave >> 1) * 64;

    f32x4 acc[4][4] = {};
    const ushort* wb = Wall + (size_t)d0 * C_;
    const int rowA = wave * 16 + (lane >> 2);
    const int fstage = ((lane >> 2) ^ (lane >> 4)) & 3;           // W staging swizzle
    const int coff = ((lane & 3) ^ fstage) * 8;
    const int fread = ((l16 & 3) ^ ((l16 >> 2) & 3));             // W read swizzle
    const bool isV = (d0 >= 768);

    // x transpose mapping: thread handles c-pair (cc,cc+1) x 8 n
    const int cc = (tid & 15) * 2;          // even c in tile
    const int nn0 = (tid >> 4) * 8;         // n-local base
    const float* xb0 = x + ((size_t)b * C_ + cc) * N_ + n0 + nn0;

    for (int c0 = 0; c0 < C_; c0 += 32) {
        // async W staging (latency hides the x transpose below)
        #pragma unroll
        for (int k = 0; k < 2; ++k)
            gl2lds16(wb + (size_t)(k * 64 + rowA) * C_ + c0 + coff,
                     &Bs[(size_t)(k * 256 + wave * 64) * 8]);
        // x fp32 -> bf16 transpose into As[n][c] (pk2 -> b32 writes, ~2-way banks)
        {
            const float* px = xb0 + (size_t)c0 * N_;
            float4 r0a = *(const float4*)px;
            float4 r0b = *(const float4*)(px + 4);
            float4 r1a = *(const float4*)(px + N_);
            float4 r1b = *(const float4*)(px + N_ + 4);
            unsigned* dst = (unsigned*)As;
            // dword index = n*17 + cc/2
            int base = nn0 * 17 + (cc >> 1);
            dst[base + 0 * 17] = pk2(r0a.x, r1a.x);
            dst[base + 1 * 17] = pk2(r0a.y, r1a.y);
            dst[base + 2 * 17] = pk2(r0a.z, r1a.z);
            dst[base + 3 * 17] = pk2(r0a.w, r1a.w);
            dst[base + 4 * 17] = pk2(r0b.x, r1b.x);
            dst[base + 5 * 17] = pk2(r0b.y, r1b.y);
            dst[base + 6 * 17] = pk2(r0b.z, r1b.z);
            dst[base + 7 * 17] = pk2(r0b.w, r1b.w);
        }
        __syncthreads();
        bf16x8 af[4], bfr[4];
        #pragma unroll
        for (int i = 0; i < 4; ++i)
            af[i] = *(const bf16x8*)&As[(wn + i * 16 + l16) * 34 + quad * 8];
        #pragma unroll
        for (int j = 0; j < 4; ++j)
            bfr[j] = *(const bf16x8*)&Bs[(wd + j * 16 + l16) * 32 + (quad ^ fread) * 8];
        if (!isV) {
            #pragma unroll
            for (int i = 0; i < 4; ++i)
                #pragma unroll
                for (int j = 0; j < 4; ++j)
                    acc[i][j] = __builtin_amdgcn_mfma_f32_16x16x32_bf16(bfr[i], af[j], acc[i][j], 0, 0, 0);
        } else {
            #pragma unroll
            for (int i = 0; i < 4; ++i)
                #pragma unroll
                for (int j = 0; j < 4; ++j)
                    acc[i][j] = __builtin_amdgcn_mfma_f32_16x16x32_bf16(af[i], bfr[j], acc[i][j], 0, 0, 0);
        }
        __syncthreads();
    }

    if (!isV) {
        // Q/K: C rows = d; lane holds 4 consecutive dc at fixed n -> packed stores
        ushort* dst = (d0 < 384) ? Qt : Kt;
        const float sc = (d0 < 384) ? C1_ : 1.0f;
        const int reg0 = (d0 < 384) ? 0 : 384;
        #pragma unroll
        for (int i = 0; i < 4; ++i) {
            int dloc = wd + i * 16;
            int dg = d0 - reg0 + dloc;
            int h = dg >> 5;
            int dc = (dg & 31) + quad * 4;
            float4 bvv = *(const float4*)(ballf + d0 + dloc + quad * 4);
            size_t hb = (size_t)(b * NH_ + h) * N_;
            #pragma unroll
            for (int j = 0; j < 4; ++j) {
                int n = n0 + wn + j * 16 + l16;
                uint2 w;
                w.x = pk2((acc[i][j][0] + bvv.x) * sc, (acc[i][j][1] + bvv.y) * sc);
                w.y = pk2((acc[i][j][2] + bvv.z) * sc, (acc[i][j][3] + bvv.w) * sc);
                *(uint2*)(dst + (hb + n) * 32 + dc) = w;
            }
        }
    } else {
        // V: C rows = n; fused transpose into Vtc[((bh*16+mc)*2+kc)*1024+dc*32+mm]
        #pragma unroll
        for (int j = 0; j < 4; ++j) {
            int dloc = wd + j * 16 + l16;
            int vd = d0 - 768 + dloc;
            int h = vd >> 5, dc = vd & 31;
            float bv = ballf[d0 + dloc];
            size_t hbase = (size_t)(b * NH_ + h) * 32768 + dc * 32;
            #pragma unroll
            for (int i = 0; i < 4; ++i) {
                int n = n0 + wn + i * 16 + quad * 4;
                size_t cbase = hbase + (size_t)((n >> 5)) * 1024 + (n & 31);
                uint2 w;
                w.x = pk2(acc[i][j][0] + bv, acc[i][j][1] + bv);
                w.y = pk2(acc[i][j][2] + bv, acc[i][j][3] + bv);
                *(uint2*)(Vtc + cbase) = w;
            }
        }
    }
}

// ---------------------------------------------------------------------------
// attn5 (r7, best known 41.5us): flash attention, S^T orientation; reversed
// bias table in LDS, C-operand float4 windows; 2 strips/wave, 768 blocks.
// ---------------------------------------------------------------------------
__global__ __launch_bounds__(256) void attn5(
    const ushort* __restrict__ Qt, const ushort* __restrict__ Kt,
    const ushort* __restrict__ Vtc, const float* __restrict__ tabT,
    ushort* __restrict__ O)
{
    const int bid = blockIdx.x;      // (b*12+h) + 96*nx
    const int bh96 = bid % 96;
    const int nx = bid / 96;
    const int b = bh96 / 12, h = bh96 % 12;

    __shared__ float tabL[TS_];
    __shared__ ushort Pa[8192];      // 4 waves x 2 strips x 16 x 64

    const int tid = threadIdx.x;
    const int lane = tid & 63, wave = tid >> 6;
    const int quad = lane >> 4, l16 = lane & 15;
    const int bh = b * NH_ + h;

    // vectorized table stage (float4; stride TS_ is 16B-aligned)
    {
        const float* th = tabT + h * TS_;
        int i = tid * 4;
        #pragma unroll
        for (int k = 0; k < 4; ++k) {
            if (i < TS_) *(float4*)&tabL[i] = *(const float4*)&th[i];
            i += 1024;
        }
    }
    __syncthreads();

    const int qs0 = nx * 8 + wave * 2;
    const ushort* Kbh = Kt + (size_t)bh * N_ * 32;
    const ushort* Vbh = Vtc + (size_t)bh * 16 * 2048;

    // Q B-frags (col=q=l16, k=dc=quad*8+j), one per strip
    bf16x8 qf[2];
    #pragma unroll
    for (int st = 0; st < 2; ++st) {
        int q = (qs0 + st) * 16 + l16;
        qf[st] = *(const bf16x8*)(Qt + ((size_t)bh * N_ + q) * 32 + quad * 8);
    }
    // reversed-table base for strip 0 (strip 1 = base - 16)
    int ibx0;
    {
        int q = qs0 * 16 + l16;
        ibx0 = (31 - (q >> 5)) * 63 + (31 - (q & 31));
    }

    f32x4 oacc[2][2] = {};
    float rs[2] = {0.f, 0.f};

    ushort* PwBase = &Pa[wave * 2048];
    const int pswz = l16 & 0xE;

    for (int mc = 0; mc < 16; ++mc) {
        // K A-frags: A[m=l16][k=quad*8+j] per 16-row tile (1KB line-contained)
        const ushort* kp = Kbh + mc * 64 * 32;
        bf16x8 k0 = *(const bf16x8*)(kp + (0 * 16 + l16) * 32 + quad * 8);
        bf16x8 k1 = *(const bf16x8*)(kp + (1 * 16 + l16) * 32 + quad * 8);
        bf16x8 k2 = *(const bf16x8*)(kp + (2 * 16 + l16) * 32 + quad * 8);
        bf16x8 k3 = *(const bf16x8*)(kp + (3 * 16 + l16) * 32 + quad * 8);
        // V^T A-frags: A[dc=dt*16+l16][m=kc*32+quad*8+j] (1KB line-contained)
        const ushort* vp = Vbh + mc * 2048;
        bf16x8 va[2][2];
        #pragma unroll
        for (int kc = 0; kc < 2; ++kc)
            #pragma unroll
            for (int dt = 0; dt < 2; ++dt)
                va[kc][dt] = *(const bf16x8*)(vp + kc * 1024 + (dt * 16 + l16) * 32 + quad * 8);

        // 6 shared bias gathers (natural-order float4 windows, broadcast-only)
        const float* Tb = tabL + ibx0 + mc * 126 + quad * 4;
        f32x4 tvm16, tv0, tv16, tv47, tv63, tv79;
        #pragma unroll
        for (int e = 0; e < 4; ++e) {
            tvm16[e] = Tb[e - 16];
            tv0[e]   = Tb[e];
            tv16[e]  = Tb[e + 16];
            tv47[e]  = Tb[e + 47];
            tv63[e]  = Tb[e + 63];
            tv79[e]  = Tb[e + 79];
        }
        // C-operand sets: st0 = {tv0, tv16, tv63, tv79}; st1 = {tvm16, tv0, tv47, tv63}
        f32x4 cbs[2][4] = {{tv0, tv16, tv63, tv79}, {tvm16, tv0, tv47, tv63}};

        #pragma unroll
        for (int st = 0; st < 2; ++st) {
            f32x4 s0 = __builtin_amdgcn_mfma_f32_16x16x32_bf16(k0, qf[st], cbs[st][0], 0, 0, 0);
            f32x4 s1 = __builtin_amdgcn_mfma_f32_16x16x32_bf16(k1, qf[st], cbs[st][1], 0, 0, 0);
            f32x4 s2 = __builtin_amdgcn_mfma_f32_16x16x32_bf16(k2, qf[st], cbs[st][2], 0, 0, 0);
            f32x4 s3 = __builtin_amdgcn_mfma_f32_16x16x32_bf16(k3, qf[st], cbs[st][3], 0, 0, 0);

            ushort* Pw = PwBase + st * 1024;
            f32x4 sv[4] = {s0, s1, s2, s3};
            #pragma unroll
            for (int t = 0; t < 4; ++t) {
                float p0 = EXP2(sv[t][0]);
                float p1 = EXP2(sv[t][1]);
                float p2 = EXP2(sv[t][2]);
                float p3 = EXP2(sv[t][3]);
                rs[st] += (p0 + p1) + (p2 + p3);
                uint2 w;
                w.x = pk2(p0, p1);
                w.y = pk2(p2, p3);
                *(uint2*)(Pw + l16 * 64 + (((t * 4 + quad) ^ pswz) * 4)) = w;
            }
            // PV: O^T[dc][q] += V^T . P   (B-frag P from swizzled LDS)
            #pragma unroll
            for (int kc = 0; kc < 2; ++kc) {
                bf16x8 pb = *(const bf16x8*)(Pw + l16 * 64 + (((kc * 8 + quad * 2) ^ pswz) * 4));
                oacc[st][0] = __builtin_amdgcn_mfma_f32_16x16x32_bf16(va[kc][0], pb, oacc[st][0], 0, 0, 0);
                oacc[st][1] = __builtin_amdgcn_mfma_f32_16x16x32_bf16(va[kc][1], pb, oacc[st][1], 0, 0, 0);
            }
        }
    }

    // row-sum: q fixed per lane; reduce across the 4 quads holding its m-slices
    #pragma unroll
    for (int st = 0; st < 2; ++st) {
        float s = rs[st];
        s += __shfl_xor(s, 16, 64);
        s += __shfl_xor(s, 32, 64);
        rs[st] = 1.0f / s;
    }

    // epilogue: O[b][q][h*32+dc], packed b64 stores
    #pragma unroll
    for (int st = 0; st < 2; ++st) {
        int q = (qs0 + st) * 16 + l16;
        ushort* ob = O + ((size_t)(b * N_ + q)) * C_ + h * HD_;
        #pragma unroll
        for (int dt = 0; dt < 2; ++dt) {
            uint2 w;
            w.x = pk2(oacc[st][dt][0] * rs[st], oacc[st][dt][1] * rs[st]);
            w.y = pk2(oacc[st][dt][2] * rs[st], oacc[st][dt][3] * rs[st]);
            *(uint2*)(ob + dt * 16 + quad * 4) = w;
        }
    }
}

// ---------------------------------------------------------------------------
// proj_gemm3: 128x128 tile, global_load_lds. A=PW[d][c], B=O[n][c].
// out[b][d][n] fp32 = acc + pb[d], coalesced along n.
// ---------------------------------------------------------------------------
__global__ __launch_bounds__(256) void proj_gemm3(
    const ushort* __restrict__ O, const ushort* __restrict__ PW,
    const float* __restrict__ pb, float* __restrict__ out)
{
    const int b = blockIdx.z, n0 = blockIdx.x * 128, d0 = blockIdx.y * 128;
    __shared__ ushort As[128 * 32];
    __shared__ ushort Bs[128 * 32];
    const int tid = threadIdx.x;
    const int lane = tid & 63, wave = tid >> 6;
    const int quad = lane >> 4, l16 = lane & 15;
    const int wa = (wave & 1) * 64, wb = (wave >> 1) * 64;

    f32x4 acc[4][4] = {};
    const ushort* ab = PW + (size_t)d0 * C_;
    const ushort* bbp = O + ((size_t)b * N_ + n0) * C_;
    const int rowA = wave * 16 + (lane >> 2);
    const int fstage = ((lane >> 2) ^ (lane >> 4)) & 3;
    const int coff = ((lane & 3) ^ fstage) * 8;
    const int fread = ((l16 & 3) ^ ((l16 >> 2) & 3));

    for (int c0 = 0; c0 < C_; c0 += 32) {
        #pragma unroll
        for (int k = 0; k < 2; ++k) {
            gl2lds16(ab + (size_t)(k * 64 + rowA) * C_ + c0 + coff,
                     &As[(size_t)(k * 256 + wave * 64) * 8]);
            gl2lds16(bbp + (size_t)(k * 64 + rowA) * C_ + c0 + coff,
                     &Bs[(size_t)(k * 256 + wave * 64) * 8]);
        }
        __syncthreads();
        bf16x8 af[4], bfr[4];
        #pragma unroll
        for (int i = 0; i < 4; ++i)
            af[i] = *(const bf16x8*)&As[(wa + i * 16 + l16) * 32 + (quad ^ fread) * 8];
        #pragma unroll
        for (int j = 0; j < 4; ++j)
            bfr[j] = *(const bf16x8*)&Bs[(wb + j * 16 + l16) * 32 + (quad ^ fread) * 8];
        #pragma unroll
        for (int i = 0; i < 4; ++i)
            #pragma unroll
            for (int j = 0; j < 4; ++j)
                acc[i][j] = __builtin_amdgcn_mfma_f32_16x16x32_bf16(af[i], bfr[j], acc[i][j], 0, 0, 0);
        __syncthreads();
    }

    #pragma unroll
    for (int i = 0; i < 4; ++i) {
        #pragma unroll
        for (int r = 0; r < 4; ++r) {
            int d = d0 + wa + i * 16 + quad * 4 + r;
            float bv = pb[d];
            float* op = out + ((size_t)b * C_ + d) * N_ + n0 + wb;
            #pragma unroll
            for (int j = 0; j < 4; ++j)
                op[j * 16 + l16] = acc[i][j][r] + bv;
        }
    }
}

// ---------------------------------------------------------------------------
extern "C" void kernel_launch(void* const* d_in, const int* in_sizes, int n_in,
                              void* d_out, int out_size, void* d_ws, size_t ws_size,
                              hipStream_t stream)
{
    const float* x      = (const float*)d_in[0];
    const float* q_w    = (const float*)d_in[1];
    const float* q_b    = (const float*)d_in[2];
    const float* kv_w   = (const float*)d_in[3];
    const float* kv_b   = (const float*)d_in[4];
    const float* proj_w = (const float*)d_in[5];
    const float* proj_b = (const float*)d_in[6];
    const float* rpb    = (const float*)d_in[7];
    float* out = (float*)d_out;

    char* ws = (char*)d_ws;
    ushort* Qt    = (ushort*)(ws);                       //  6,291,456
    ushort* Kt    = (ushort*)(ws +  6291456);            //  6,291,456
    ushort* Vtc   = (ushort*)(ws + 12582912);            //  6,291,456
    ushort* O     = (ushort*)(ws + 18874368);            //  6,291,456
    float*  tabT  = (float*) (ws + 25165824);            //    190,656 (12 x 3972 x 4)
    ushort* Wall  = (ushort*)(ws + 25356480);            //    884,736
    ushort* PW    = (ushort*)(ws + 26241216);            //    294,912
    float*  ballf = (float*) (ws + 26536128);            //      4,608

    setup2     <<<dim3(590), 256, 0, stream>>>(q_w, kv_w, proj_w, q_b, kv_b, rpb,
                                               tabT, Wall, PW, ballf);
    qkv_gemm6  <<<dim3(8, 9, B_), 256, 0, stream>>>(x, Wall, ballf, Qt, Kt, Vtc);
    attn5      <<<dim3(768), 256, 0, stream>>>(Qt, Kt, Vtc, tabT, O);
    proj_gemm3 <<<dim3(8, 3, B_), 256, 0, stream>>>(O, PW, proj_b, out);
}

// Round 12
// 149.780 us; speedup vs baseline: 1.1049x; 1.1049x over previous
//
#include <hip/hip_runtime.h>
#include <hip/hip_bf16.h>

#define B_  8
#define C_  384
#define N_  1024
#define NH_ 12
#define HD_ 32
#define D3_ 1152   // 3*C

typedef __bf16 bf16x8 __attribute__((ext_vector_type(8)));
typedef __bf16 bf16x2 __attribute__((ext_vector_type(2)));
typedef float  f32x4  __attribute__((ext_vector_type(4)));

typedef const __attribute__((address_space(1))) unsigned int guint;
typedef __attribute__((address_space(3))) unsigned int luint;

__device__ __forceinline__ float b2f(ushort u) {
    return __uint_as_float(((unsigned int)u) << 16);
}
__device__ __forceinline__ ushort f2b(float f) {
    unsigned int i = __float_as_uint(f);
    unsigned int r = i + 0x7fffu + ((i >> 16) & 1u);  // RNE
    return (ushort)(r >> 16);
}
// packed fp32x2 -> bf16x2 (RNE)
__device__ __forceinline__ unsigned pk2(float a, float b) {
#if __has_builtin(__builtin_amdgcn_cvt_pk_bf16_f32)
    bf16x2 t = __builtin_amdgcn_cvt_pk_bf16_f32(a, b);
    return __builtin_bit_cast(unsigned, t);
#else
    return (unsigned)f2b(a) | ((unsigned)f2b(b) << 16);
#endif
}

#if __has_builtin(__builtin_amdgcn_exp2f)
#define EXP2 __builtin_amdgcn_exp2f
#else
#define EXP2 exp2f
#endif

__device__ __forceinline__ void gl2lds16(const void* g, void* l) {
    __builtin_amdgcn_global_load_lds((guint*)g, (luint*)l, 16, 0, 0);
}

#define C1_ 0.25505654204433796f   // scale * log2e
#define C2_ 1.4426950408889634f    // log2e
#define TS_ 3972                   // padded per-head table stride (16B-aligned)

// ---------------------------------------------------------------------------
// setup: x-transpose + weight conversion + bias-table prep.  (r7-verified)
// Grid: [0,768) xtrans, [768,1346) prep, [1346,1358) tabT.
// tabT[h][i] = rpb[3968-i][h] * log2e   (full 2D reversal == 1D reversal)
// ---------------------------------------------------------------------------
__global__ __launch_bounds__(256) void setup(
    const float* __restrict__ x, const float* __restrict__ q_w,
    const float* __restrict__ kv_w, const float* __restrict__ proj_w,
    const float* __restrict__ q_b, const float* __restrict__ kv_b,
    const float* __restrict__ tab,
    ushort* __restrict__ xT, float* __restrict__ tabT,
    ushort* __restrict__ Wall, ushort* __restrict__ PW,
    float* __restrict__ ballf)
{
    __shared__ ushort T[64 * 72];
    const int bx = blockIdx.x, tid = threadIdx.x;

    if (bx < 768) {
        // ---- xtrans: x[b][c][n] fp32 -> xT[b][n][c] bf16 (line-contained both sides)
        int t = bx;
        int nx = t & 15, cy = (t >> 4) % 6, b = t / 96;
        int n0 = nx * 64, c0 = cy * 64;
        {
            int i = tid >> 2;            // c-local
            int ns = (tid & 3) * 16;     // n-local
            const float* src = x + ((size_t)b * C_ + c0 + i) * N_ + n0 + ns;
            #pragma unroll
            for (int k4 = 0; k4 < 4; ++k4) {
                float4 f = *(const float4*)(src + k4 * 4);
                T[(ns + k4 * 4 + 0) * 72 + i] = f2b(f.x);
                T[(ns + k4 * 4 + 1) * 72 + i] = f2b(f.y);
                T[(ns + k4 * 4 + 2) * 72 + i] = f2b(f.z);
                T[(ns + k4 * 4 + 3) * 72 + i] = f2b(f.w);
            }
        }
        __syncthreads();
        {
            int j = tid >> 2;            // n-local
            int cs = (tid & 3) * 16;     // c-local
            ushort* dst = xT + ((size_t)b * N_ + n0 + j) * C_ + c0 + cs;
            *(uint4*)dst       = *(const uint4*)&T[j * 72 + cs];
            *(uint4*)(dst + 8) = *(const uint4*)&T[j * 72 + cs + 8];
        }
    } else if (bx < 1346) {
        // ---- prep: weights fp32 -> bf16; bias concat fp32 ----
        const int NW4 = 110592, NP4 = 36864, NB4 = 288;
        int t = (bx - 768) * 256 + tid;
        if (t < NW4) {
            int e = t * 4;
            float4 f = (e < 147456) ? *(const float4*)(q_w + e)
                                    : *(const float4*)(kv_w + e - 147456);
            union { uint2 u; ushort s[4]; } o;
            o.u.x = pk2(f.x, f.y); o.u.y = pk2(f.z, f.w);
            *(uint2*)(Wall + e) = o.u;
        } else if (t < NW4 + NP4) {
            int e = (t - NW4) * 4;
            float4 f = *(const float4*)(proj_w + e);
            union { uint2 u; ushort s[4]; } o;
            o.u.x = pk2(f.x, f.y); o.u.y = pk2(f.z, f.w);
            *(uint2*)(PW + e) = o.u;
        } else if (t < NW4 + NP4 + NB4) {
            int e = (t - NW4 - NP4) * 4;
            float4 f = (e < 384) ? *(const float4*)(q_b + e)
                                 : *(const float4*)(kv_b + e - 384);
            *(float4*)(ballf + e) = f;
        }
    } else {
        // ---- tabT: per-head fully-reversed, log2e-scaled table ----
        int h = bx - 1346;
        for (int i = tid; i < 3969; i += 256)
            tabT[h * TS_ + i] = tab[(size_t)(3968 - i) * NH_ + h] * C2_;
        if (tid < 3) tabT[h * TS_ + 3969 + tid] = 0.0f;
    }
}

// ---------------------------------------------------------------------------
// qkv_gemm5 (r7-verified): 128x128 tile, global_load_lds, XOR-swizzled LDS.
// Q/K blocks: W as A-operand -> packed 8B stores to Qt/Kt[b][h][n][32].
// V blocks:   x as A-operand -> fused-transpose packed stores to Vtc.
// Q pre-scaled by scale*log2e.
// ---------------------------------------------------------------------------
__global__ __launch_bounds__(256) void qkv_gemm5(
    const ushort* __restrict__ xT, const ushort* __restrict__ Wall,
    const float* __restrict__ ballf, ushort* __restrict__ Qt,
    ushort* __restrict__ Kt, ushort* __restrict__ Vtc)
{
    const int b = blockIdx.z, n0 = blockIdx.x * 128, d0 = blockIdx.y * 128;
    __shared__ ushort As[128 * 32];
    __shared__ ushort Bs[128 * 32];
    const int tid = threadIdx.x;
    const int lane = tid & 63, wave = tid >> 6;
    const int quad = lane >> 4, l16 = lane & 15;
    const int wn = (wave & 1) * 64, wd = (wave >> 1) * 64;

    f32x4 acc[4][4] = {};
    const ushort* xb = xT + ((size_t)b * N_ + n0) * C_;
    const ushort* wb = Wall + (size_t)d0 * C_;
    const int rowA = wave * 16 + (lane >> 2);
    const int fstage = ((lane >> 2) ^ (lane >> 4)) & 3;           // staging swizzle
    const int coff = ((lane & 3) ^ fstage) * 8;
    const int fread = ((l16 & 3) ^ ((l16 >> 2) & 3));             // read swizzle
    const bool isV = (d0 >= 768);

    for (int c0 = 0; c0 < C_; c0 += 32) {
        #pragma unroll
        for (int k = 0; k < 2; ++k) {
            gl2lds16(xb + (size_t)(k * 64 + rowA) * C_ + c0 + coff,
                     &As[(size_t)(k * 256 + wave * 64) * 8]);
            gl2lds16(wb + (size_t)(k * 64 + rowA) * C_ + c0 + coff,
                     &Bs[(size_t)(k * 256 + wave * 64) * 8]);
        }
        __syncthreads();
        bf16x8 af[4], bfr[4];
        #pragma unroll
        for (int i = 0; i < 4; ++i)
            af[i] = *(const bf16x8*)&As[(wn + i * 16 + l16) * 32 + (quad ^ fread) * 8];
        #pragma unroll
        for (int j = 0; j < 4; ++j)
            bfr[j] = *(const bf16x8*)&Bs[(wd + j * 16 + l16) * 32 + (quad ^ fread) * 8];
        if (!isV) {
            #pragma unroll
            for (int i = 0; i < 4; ++i)
                #pragma unroll
                for (int j = 0; j < 4; ++j)
                    acc[i][j] = __builtin_amdgcn_mfma_f32_16x16x32_bf16(bfr[i], af[j], acc[i][j], 0, 0, 0);
        } else {
            #pragma unroll
            for (int i = 0; i < 4; ++i)
                #pragma unroll
                for (int j = 0; j < 4; ++j)
                    acc[i][j] = __builtin_amdgcn_mfma_f32_16x16x32_bf16(af[i], bfr[j], acc[i][j], 0, 0, 0);
        }
        __syncthreads();
    }

    if (!isV) {
        ushort* dst = (d0 < 384) ? Qt : Kt;
        const float sc = (d0 < 384) ? C1_ : 1.0f;
        const int reg0 = (d0 < 384) ? 0 : 384;
        #pragma unroll
        for (int i = 0; i < 4; ++i) {
            int dloc = wd + i * 16;
            int dg = d0 - reg0 + dloc;
            int h = dg >> 5;
            int dc = (dg & 31) + quad * 4;
            float4 bvv = *(const float4*)(ballf + d0 + dloc + quad * 4);
            size_t hb = (size_t)(b * NH_ + h) * N_;
            #pragma unroll
            for (int j = 0; j < 4; ++j) {
                int n = n0 + wn + j * 16 + l16;
                uint2 w;
                w.x = pk2((acc[i][j][0] + bvv.x) * sc, (acc[i][j][1] + bvv.y) * sc);
                w.y = pk2((acc[i][j][2] + bvv.z) * sc, (acc[i][j][3] + bvv.w) * sc);
                *(uint2*)(dst + (hb + n) * 32 + dc) = w;
            }
        }
    } else {
        #pragma unroll
        for (int j = 0; j < 4; ++j) {
            int dloc = wd + j * 16 + l16;
            int vd = d0 - 768 + dloc;
            int h = vd >> 5, dc = vd & 31;
            float bv = ballf[d0 + dloc];
            size_t hbase = (size_t)(b * NH_ + h) * 32768 + dc * 32;
            #pragma unroll
            for (int i = 0; i < 4; ++i) {
                int n = n0 + wn + i * 16 + quad * 4;
                size_t cbase = hbase + (size_t)((n >> 5)) * 1024 + (n & 31);
                uint2 w;
                w.x = pk2(acc[i][j][0] + bv, acc[i][j][1] + bv);
                w.y = pk2(acc[i][j][2] + bv, acc[i][j][3] + bv);
                *(uint2*)(Vtc + cbase) = w;
            }
        }
    }
}

// ---------------------------------------------------------------------------
// attn9: r7's attn5 + ones-MFMA rowsum (only change). S^T orientation,
// reversed bias table in LDS as MFMA C-operand, 2 strips/wave, 768 blocks.
// Rowsum on the matrix pipe removes 16 serial VALU adds per strip-chunk
// (they sat on the exp2 critical path) and the two end shuffles.
// ---------------------------------------------------------------------------
__global__ __launch_bounds__(256) void attn9(
    const ushort* __restrict__ Qt, const ushort* __restrict__ Kt,
    const ushort* __restrict__ Vtc, const float* __restrict__ tabT,
    ushort* __restrict__ O)
{
    const int bid = blockIdx.x;      // (b*12+h) + 96*nx
    const int bh96 = bid % 96;
    const int nx = bid / 96;
    const int b = bh96 / 12, h = bh96 % 12;

    __shared__ float tabL[TS_];
    __shared__ ushort Pa[8192];      // 4 waves x 2 strips x 16 x 64

    const int tid = threadIdx.x;
    const int lane = tid & 63, wave = tid >> 6;
    const int quad = lane >> 4, l16 = lane & 15;
    const int bh = b * NH_ + h;

    // vectorized table stage (float4; stride TS_ is 16B-aligned)
    {
        const float* th = tabT + h * TS_;
        int i = tid * 4;
        #pragma unroll
        for (int k = 0; k < 4; ++k) {
            if (i < TS_) *(float4*)&tabL[i] = *(const float4*)&th[i];
            i += 1024;
        }
    }
    __syncthreads();

    const int qs0 = nx * 8 + wave * 2;
    const ushort* Kbh = Kt + (size_t)bh * N_ * 32;
    const ushort* Vbh = Vtc + (size_t)bh * 16 * 2048;

    // Q B-frags (col=q=l16, k=dc=quad*8+j), one per strip
    bf16x8 qf[2];
    #pragma unroll
    for (int st = 0; st < 2; ++st) {
        int q = (qs0 + st) * 16 + l16;
        qf[st] = *(const bf16x8*)(Qt + ((size_t)bh * N_ + q) * 32 + quad * 8);
    }
    // reversed-table base for strip 0 (strip 1 = base - 16)
    int ibx0;
    {
        int q = qs0 * 16 + l16;
        ibx0 = (31 - (q >> 5)) * 63 + (31 - (q & 31));
    }

    bf16x8 ones;
    #pragma unroll
    for (int j = 0; j < 8; ++j) ones[j] = (__bf16)1.0f;

    f32x4 oacc[2][2] = {};
    f32x4 lacc[2] = {};

    ushort* PwBase = &Pa[wave * 2048];
    const int pswz = l16 & 0xE;

    for (int mc = 0; mc < 16; ++mc) {
        // K A-frags: A[m=l16][k=quad*8+j] per 16-row tile (1KB line-contained)
        const ushort* kp = Kbh + mc * 64 * 32;
        bf16x8 k0 = *(const bf16x8*)(kp + (0 * 16 + l16) * 32 + quad * 8);
        bf16x8 k1 = *(const bf16x8*)(kp + (1 * 16 + l16) * 32 + quad * 8);
        bf16x8 k2 = *(const bf16x8*)(kp + (2 * 16 + l16) * 32 + quad * 8);
        bf16x8 k3 = *(const bf16x8*)(kp + (3 * 16 + l16) * 32 + quad * 8);
        // V^T A-frags: A[dc=dt*16+l16][m=kc*32+quad*8+j] (1KB line-contained)
        const ushort* vp = Vbh + mc * 2048;
        bf16x8 va[2][2];
        #pragma unroll
        for (int kc = 0; kc < 2; ++kc)
            #pragma unroll
            for (int dt = 0; dt < 2; ++dt)
                va[kc][dt] = *(const bf16x8*)(vp + kc * 1024 + (dt * 16 + l16) * 32 + quad * 8);

        // 6 shared bias gathers (natural-order float4 windows, broadcast-only)
        const float* Tb = tabL + ibx0 + mc * 126 + quad * 4;
        f32x4 tvm16, tv0, tv16, tv47, tv63, tv79;
        #pragma unroll
        for (int e = 0; e < 4; ++e) {
            tvm16[e] = Tb[e - 16];
            tv0[e]   = Tb[e];
            tv16[e]  = Tb[e + 16];
            tv47[e]  = Tb[e + 47];
            tv63[e]  = Tb[e + 63];
            tv79[e]  = Tb[e + 79];
        }
        // C-operand sets: st0 = {tv0, tv16, tv63, tv79}; st1 = {tvm16, tv0, tv47, tv63}
        f32x4 cbs[2][4] = {{tv0, tv16, tv63, tv79}, {tvm16, tv0, tv47, tv63}};

        #pragma unroll
        for (int st = 0; st < 2; ++st) {
            f32x4 s0 = __builtin_amdgcn_mfma_f32_16x16x32_bf16(k0, qf[st], cbs[st][0], 0, 0, 0);
            f32x4 s1 = __builtin_amdgcn_mfma_f32_16x16x32_bf16(k1, qf[st], cbs[st][1], 0, 0, 0);
            f32x4 s2 = __builtin_amdgcn_mfma_f32_16x16x32_bf16(k2, qf[st], cbs[st][2], 0, 0, 0);
            f32x4 s3 = __builtin_amdgcn_mfma_f32_16x16x32_bf16(k3, qf[st], cbs[st][3], 0, 0, 0);

            ushort* Pw = PwBase + st * 1024;
            f32x4 sv[4] = {s0, s1, s2, s3};
            #pragma unroll
            for (int t = 0; t < 4; ++t) {
                float p0 = EXP2(sv[t][0]);
                float p1 = EXP2(sv[t][1]);
                float p2 = EXP2(sv[t][2]);
                float p3 = EXP2(sv[t][3]);
                uint2 w;
                w.x = pk2(p0, p1);
                w.y = pk2(p2, p3);
                *(uint2*)(Pw + l16 * 64 + (((t * 4 + quad) ^ pswz) * 4)) = w;
            }
            // PV + rowsum: O^T[dc][q] += V^T . P ; l[q] += ones . P  (matrix pipe)
            #pragma unroll
            for (int kc = 0; kc < 2; ++kc) {
                bf16x8 pb = *(const bf16x8*)(Pw + l16 * 64 + (((kc * 8 + quad * 2) ^ pswz) * 4));
                lacc[st]    = __builtin_amdgcn_mfma_f32_16x16x32_bf16(ones, pb, lacc[st], 0, 0, 0);
                oacc[st][0] = __builtin_amdgcn_mfma_f32_16x16x32_bf16(va[kc][0], pb, oacc[st][0], 0, 0, 0);
                oacc[st][1] = __builtin_amdgcn_mfma_f32_16x16x32_bf16(va[kc][1], pb, oacc[st][1], 0, 0, 0);
            }
        }
    }

    // epilogue: O[b][q][h*32+dc], packed b64 stores (lacc rows all equal = rowsum)
    #pragma unroll
    for (int st = 0; st < 2; ++st) {
        float inv = 1.0f / lacc[st][0];
        int q = (qs0 + st) * 16 + l16;
        ushort* ob = O + ((size_t)(b * N_ + q)) * C_ + h * HD_;
        #pragma unroll
        for (int dt = 0; dt < 2; ++dt) {
            uint2 w;
            w.x = pk2(oacc[st][dt][0] * inv, oacc[st][dt][1] * inv);
            w.y = pk2(oacc[st][dt][2] * inv, oacc[st][dt][3] * inv);
            *(uint2*)(ob + dt * 16 + quad * 4) = w;
        }
    }
}

// ---------------------------------------------------------------------------
// proj_gemm3 (r7-verified): 128x128 tile, global_load_lds. A=PW[d][c], B=O[n][c].
// out[b][d][n] fp32 = acc + pb[d], coalesced along n.
// ---------------------------------------------------------------------------
__global__ __launch_bounds__(256) void proj_gemm3(
    const ushort* __restrict__ O, const ushort* __restrict__ PW,
    const float* __restrict__ pb, float* __restrict__ out)
{
    const int b = blockIdx.z, n0 = blockIdx.x * 128, d0 = blockIdx.y * 128;
    __shared__ ushort As[128 * 32];
    __shared__ ushort Bs[128 * 32];
    const int tid = threadIdx.x;
    const int lane = tid & 63, wave = tid >> 6;
    const int quad = lane >> 4, l16 = lane & 15;
    const int wa = (wave & 1) * 64, wb = (wave >> 1) * 64;

    f32x4 acc[4][4] = {};
    const ushort* ab = PW + (size_t)d0 * C_;
    const ushort* bbp = O + ((size_t)b * N_ + n0) * C_;
    const int rowA = wave * 16 + (lane >> 2);
    const int fstage = ((lane >> 2) ^ (lane >> 4)) & 3;
    const int coff = ((lane & 3) ^ fstage) * 8;
    const int fread = ((l16 & 3) ^ ((l16 >> 2) & 3));

    for (int c0 = 0; c0 < C_; c0 += 32) {
        #pragma unroll
        for (int k = 0; k < 2; ++k) {
            gl2lds16(ab + (size_t)(k * 64 + rowA) * C_ + c0 + coff,
                     &As[(size_t)(k * 256 + wave * 64) * 8]);
            gl2lds16(bbp + (size_t)(k * 64 + rowA) * C_ + c0 + coff,
                     &Bs[(size_t)(k * 256 + wave * 64) * 8]);
        }
        __syncthreads();
        bf16x8 af[4], bfr[4];
        #pragma unroll
        for (int i = 0; i < 4; ++i)
            af[i] = *(const bf16x8*)&As[(wa + i * 16 + l16) * 32 + (quad ^ fread) * 8];
        #pragma unroll
        for (int j = 0; j < 4; ++j)
            bfr[j] = *(const bf16x8*)&Bs[(wb + j * 16 + l16) * 32 + (quad ^ fread) * 8];
        #pragma unroll
        for (int i = 0; i < 4; ++i)
            #pragma unroll
            for (int j = 0; j < 4; ++j)
                acc[i][j] = __builtin_amdgcn_mfma_f32_16x16x32_bf16(af[i], bfr[j], acc[i][j], 0, 0, 0);
        __syncthreads();
    }

    #pragma unroll
    for (int i = 0; i < 4; ++i) {
        #pragma unroll
        for (int r = 0; r < 4; ++r) {
            int d = d0 + wa + i * 16 + quad * 4 + r;
            float bv = pb[d];
            float* op = out + ((size_t)b * C_ + d) * N_ + n0 + wb;
            #pragma unroll
            for (int j = 0; j < 4; ++j)
                op[j * 16 + l16] = acc[i][j][r] + bv;
        }
    }
}

// ---------------------------------------------------------------------------
extern "C" void kernel_launch(void* const* d_in, const int* in_sizes, int n_in,
                              void* d_out, int out_size, void* d_ws, size_t ws_size,
                              hipStream_t stream)
{
    const float* x      = (const float*)d_in[0];
    const float* q_w    = (const float*)d_in[1];
    const float* q_b    = (const float*)d_in[2];
    const float* kv_w   = (const float*)d_in[3];
    const float* kv_b   = (const float*)d_in[4];
    const float* proj_w = (const float*)d_in[5];
    const float* proj_b = (const float*)d_in[6];
    const float* rpb    = (const float*)d_in[7];
    float* out = (float*)d_out;

    char* ws = (char*)d_ws;
    ushort* xT    = (ushort*)(ws);                       //  6,291,456
    ushort* Qt    = (ushort*)(ws +  6291456);            //  6,291,456
    ushort* Kt    = (ushort*)(ws + 12582912);            //  6,291,456
    ushort* Vtc   = (ushort*)(ws + 18874368);            //  6,291,456
    ushort* O     = (ushort*)(ws + 25165824);            //  6,291,456
    float*  tabT  = (float*) (ws + 31457280);            //    190,656 (12 x 3972 x 4)
    ushort* Wall  = (ushort*)(ws + 31647936);            //    884,736
    ushort* PW    = (ushort*)(ws + 32532672);            //    294,912
    float*  ballf = (float*) (ws + 32827584);            //      4,608

    setup      <<<dim3(1358), 256, 0, stream>>>(x, q_w, kv_w, proj_w, q_b, kv_b, rpb,
                                                xT, tabT, Wall, PW, ballf);
    qkv_gemm5  <<<dim3(8, 9, B_), 256, 0, stream>>>(xT, Wall, ballf, Qt, Kt, Vtc);
    attn9      <<<dim3(768), 256, 0, stream>>>(Qt, Kt, Vtc, tabT, O);
    proj_gemm3 <<<dim3(8, 3, B_), 256, 0, stream>>>(O, PW, proj_b, out);
}